// Round 1
// baseline (81.259 us; speedup 1.0000x reference)
//
#include <hip/hip_runtime.h>

// Upsample1d (linear kernel, reflect pad), stride-2 transposed depthwise FIR.
// Math (verified against reference):
//   x = reflect-pad(h, 1)            -> x[i] = h[i-1], x[0]=h[1], x[L+1]=h[L-2]
//   out[n] = sum_k w[k]*xd[n+k],  w = kernel[::-1], xd = 2x-dilated x
//   => out[2m]   = kernel[3]*h[m-1] + kernel[1]*h[m]   (h[-1] := h[1])
//      out[2m+1] = kernel[2]*h[m]   + kernel[0]*h[m+1] (h[L]  := h[L-2])
//
// Memory-bound: 134 MB read + 268 MB write. One thread handles 4 input elems
// (float4 load) -> 8 output elems (two float4 stores).

__global__ __launch_bounds__(256) void upsample1d_kernel(
    const float* __restrict__ h, const float* __restrict__ ker,
    float* __restrict__ out, int L) {
    const int tpr = L >> 2;               // threads per row (L/4)
    const int row = blockIdx.y;           // one (b,c) row per blockIdx.y
    const int pos = blockIdx.x * blockDim.x + threadIdx.x;
    if (pos >= tpr) return;

    const float* __restrict__ hr = h + (long long)row * L;
    float* __restrict__ orow = out + (long long)row * 2 * L;

    const int i0 = pos << 2;              // first input index for this thread
    const float4 v = *reinterpret_cast<const float4*>(hr + i0);

    // neighbors (reflect at the row edges)
    const float left  = (pos > 0)       ? hr[i0 - 1] : v.y;  // h[-1] = h[1]
    const float right = (pos < tpr - 1) ? hr[i0 + 4] : v.z;  // h[L]  = h[L-2]

    const float k0 = ker[0], k1 = ker[1], k2 = ker[2], k3 = ker[3];

    const float e[4]   = {v.x, v.y, v.z, v.w};
    const float lft[4] = {left, v.x, v.y, v.z};
    const float rgt[4] = {v.y, v.z, v.w, right};

    float o[8];
#pragma unroll
    for (int j = 0; j < 4; ++j) {
        o[2 * j]     = k3 * lft[j] + k1 * e[j];
        o[2 * j + 1] = k2 * e[j]   + k0 * rgt[j];
    }

    *reinterpret_cast<float4*>(orow + 2 * i0)     = make_float4(o[0], o[1], o[2], o[3]);
    *reinterpret_cast<float4*>(orow + 2 * i0 + 4) = make_float4(o[4], o[5], o[6], o[7]);
}

extern "C" void kernel_launch(void* const* d_in, const int* in_sizes, int n_in,
                              void* d_out, int out_size, void* d_ws, size_t ws_size,
                              hipStream_t stream) {
    const float* h   = (const float*)d_in[0];
    const float* ker = (const float*)d_in[1];
    float* out = (float*)d_out;

    const int L = 8192;                       // fixed by the reference problem
    const int nrows = in_sizes[0] / L;        // B*C = 4096
    const int tpr = L / 4;                    // 2048 threads per row
    const int block = 256;
    dim3 grid(tpr / block, nrows);            // (8, 4096)

    upsample1d_kernel<<<grid, block, 0, stream>>>(h, ker, out, L);
}